// Round 1
// baseline (4998.304 us; speedup 1.0000x reference)
//
#include <hip/hip_runtime.h>

#define N_NODES 500000
#define N_EDGES 2000000
#define N_GRAPHS 16384

// ---------------- degree / dinv ----------------
__global__ __launch_bounds__(256) void k_init_deg(float* deg) {
    int i = blockIdx.x * 256 + threadIdx.x;
    if (i < N_NODES) deg[i] = 1.0f;
}
__global__ __launch_bounds__(256) void k_count(const int* __restrict__ dst, float* __restrict__ deg) {
    int e = blockIdx.x * 256 + threadIdx.x;
    if (e < N_EDGES) atomicAdd(&deg[dst[e]], 1.0f);
}
__global__ __launch_bounds__(256) void k_rsqrt(float* deg) {
    int i = blockIdx.x * 256 + threadIdx.x;
    if (i < N_NODES) deg[i] = rsqrtf(deg[i]);
}

// ---------------- rowwise GEMM for conv layers: out[M,N] = X[M,K] @ W[K,N] ----------------
// M must be divisible by RPB. Optional relu on X load.
template<int K, int N, bool RELU_IN>
__global__ __launch_bounds__(256) void k_rowgemm(const float* __restrict__ X,
                                                 const float* __restrict__ W,
                                                 float* __restrict__ out) {
    constexpr int TPR = N / 4;        // threads per row
    constexpr int RPB = 256 / TPR;    // rows per block
    __shared__ float xs[RPB][K];
    const int r0 = blockIdx.x * RPB;
    for (int i = threadIdx.x; i < RPB * K; i += 256) {
        int r = i / K, k = i % K;
        float v = X[(size_t)(r0 + r) * K + k];
        xs[r][k] = RELU_IN ? fmaxf(v, 0.0f) : v;
    }
    __syncthreads();
    const int r  = threadIdx.x / TPR;
    const int c0 = (threadIdx.x % TPR) * 4;
    const int row = r0 + r;
    float4 acc = {0.f, 0.f, 0.f, 0.f};
    #pragma unroll 4
    for (int k = 0; k < K; k++) {
        float xv = xs[r][k];
        float4 w = *(const float4*)(W + (size_t)k * N + c0);
        acc.x = fmaf(xv, w.x, acc.x);
        acc.y = fmaf(xv, w.y, acc.y);
        acc.z = fmaf(xv, w.z, acc.z);
        acc.w = fmaf(xv, w.w, acc.w);
    }
    *(float4*)(out + (size_t)row * N + c0) = acc;
}

// ---------------- agg init: agg = dinv^2 * h + bias ----------------
template<int N>
__global__ __launch_bounds__(256) void k_init_agg(const float* __restrict__ h,
                                                  const float* __restrict__ dinv,
                                                  const float* __restrict__ bias,
                                                  float* __restrict__ agg) {
    size_t i = (size_t)blockIdx.x * 256 + threadIdx.x;  // index of float4
    size_t total = (size_t)N_NODES * N / 4;
    if (i >= total) return;
    size_t e0 = i * 4;
    int row = (int)(e0 / N);
    int c   = (int)(e0 % N);
    float d = dinv[row];
    float s = d * d;
    float4 hv = *(const float4*)(h + e0);
    float4 b  = *(const float4*)(bias + c);
    float4 o;
    o.x = fmaf(s, hv.x, b.x);
    o.y = fmaf(s, hv.y, b.y);
    o.z = fmaf(s, hv.z, b.z);
    o.w = fmaf(s, hv.w, b.w);
    *(float4*)(agg + e0) = o;
}

// ---------------- edge scatter: agg[dst] += dinv[src]*dinv[dst]*h[src] ----------------
// one wave (64 lanes) per edge
template<int N>
__global__ __launch_bounds__(256) void k_scatter(const int* __restrict__ src,
                                                 const int* __restrict__ dst,
                                                 const float* __restrict__ dinv,
                                                 const float* __restrict__ h,
                                                 float* __restrict__ agg) {
    int g = blockIdx.x * 256 + threadIdx.x;
    int e = g >> 6, lane = g & 63;
    if (e >= N_EDGES) return;
    int s = src[e], d = dst[e];
    float nrm = dinv[s] * dinv[d];
    if (N == 128) {
        float2 hv = *(const float2*)(h + (size_t)s * 128 + lane * 2);
        atomicAdd(&agg[(size_t)d * 128 + lane * 2 + 0], nrm * hv.x);
        atomicAdd(&agg[(size_t)d * 128 + lane * 2 + 1], nrm * hv.y);
    } else {
        float hv = h[(size_t)s * 64 + lane];
        atomicAdd(&agg[(size_t)d * 64 + lane], nrm * hv);
    }
}

// ---------------- zpad init: [G, 80] = [pool(0..63) | solvent(64..74) | zeros] ----------------
__global__ __launch_bounds__(256) void k_zpad_init(const float* __restrict__ solv, float* __restrict__ zpad) {
    int i = blockIdx.x * 256 + threadIdx.x;
    if (i >= N_GRAPHS * 80) return;
    int g = i / 80, c = i % 80;
    float v = 0.0f;
    if (c >= 64 && c < 75) v = solv[g * 11 + (c - 64)];
    zpad[i] = v;
}

// ---------------- pool: zpad[batch[n], 0..63] += agg2[n, :] ----------------
__global__ __launch_bounds__(256) void k_pool(const float* __restrict__ agg,
                                              const int* __restrict__ batch,
                                              float* __restrict__ zpad) {
    int g = blockIdx.x * 256 + threadIdx.x;
    int n = g >> 6, lane = g & 63;
    if (n >= N_NODES) return;
    int b = batch[n];
    atomicAdd(&zpad[(size_t)b * 80 + lane], agg[(size_t)n * 64 + lane]);
}

// ---------------- W1 pad 75->80 rows ----------------
__global__ __launch_bounds__(256) void k_w1pad(const float* __restrict__ W1, float* __restrict__ w1pad) {
    int i = blockIdx.x * 256 + threadIdx.x;
    if (i >= 80 * 2048) return;
    int r = i / 2048, c = i % 2048;
    w1pad[i] = (r < 75) ? W1[r * 2048 + c] : 0.0f;
}

// ---------------- heads weight concat: whcat[f, h*32+k] = Wh1[h,f,k], padded to 256 cols ----------------
__global__ __launch_bounds__(256) void k_whcat(const float* __restrict__ Wh1, float* __restrict__ whcat) {
    int i = blockIdx.x * 256 + threadIdx.x;
    if (i >= 128 * 256) return;
    int f = i / 256, c = i % 256;
    float v = 0.0f;
    if (c < 192) {
        int h = c / 32, k = c & 31;
        v = Wh1[h * 128 * 32 + f * 32 + k];
    }
    whcat[i] = v;
}
__global__ __launch_bounds__(256) void k_bh1pad(const float* __restrict__ bh1, float* __restrict__ bh1pad) {
    int i = threadIdx.x;
    bh1pad[i] = (i < 192) ? bh1[i] : 0.0f;
}

// ---------------- tiled fp32 GEMM: C[M,N] = act(A[M,K] @ B[K,N] + bias) ----------------
// BM=BN=128, BK=8, 256 threads, 8x8 per thread. M%128==0, N%128==0, K%8==0.
template<bool RELU>
__global__ __launch_bounds__(256) void k_gemm(const float* __restrict__ A,
                                              const float* __restrict__ B,
                                              const float* __restrict__ bias,
                                              float* __restrict__ C,
                                              int M, int N, int K) {
    __shared__ float As[8][132];
    __shared__ float Bs[8][132];
    const int tid = threadIdx.x;
    const int bm = blockIdx.y, bn = blockIdx.x;
    const int tr = (tid >> 4) << 3;   // 0..120
    const int tc = (tid & 15) << 3;   // 0..120
    float acc[8][8] = {};
    const float* Ab = A + (size_t)bm * 128 * K;
    const float* Bb = B + (size_t)bn * 128;
    const int la_r = tid >> 1, la_c = (tid & 1) << 2;   // A tile 128x8
    const int lb_r = tid >> 5, lb_c = (tid & 31) << 2;  // B tile 8x128
    for (int k0 = 0; k0 < K; k0 += 8) {
        float4 a4 = *(const float4*)(Ab + (size_t)la_r * K + k0 + la_c);
        float4 b4 = *(const float4*)(Bb + (size_t)(k0 + lb_r) * N + lb_c);
        __syncthreads();
        As[la_c + 0][la_r] = a4.x;
        As[la_c + 1][la_r] = a4.y;
        As[la_c + 2][la_r] = a4.z;
        As[la_c + 3][la_r] = a4.w;
        *(float4*)&Bs[lb_r][lb_c] = b4;
        __syncthreads();
        #pragma unroll
        for (int k = 0; k < 8; k++) {
            float a[8], b[8];
            *(float4*)&a[0] = *(const float4*)&As[k][tr];
            *(float4*)&a[4] = *(const float4*)&As[k][tr + 4];
            *(float4*)&b[0] = *(const float4*)&Bs[k][tc];
            *(float4*)&b[4] = *(const float4*)&Bs[k][tc + 4];
            #pragma unroll
            for (int i = 0; i < 8; i++)
                #pragma unroll
                for (int j = 0; j < 8; j++)
                    acc[i][j] = fmaf(a[i], b[j], acc[i][j]);
        }
    }
    const int row0 = bm * 128 + tr, col0 = bn * 128 + tc;
    #pragma unroll
    for (int i = 0; i < 8; i++) {
        #pragma unroll
        for (int j = 0; j < 8; j++) {
            float v = acc[i][j] + bias[col0 + j];
            if (RELU) v = fmaxf(v, 0.0f);
            acc[i][j] = v;
        }
        *(float4*)(C + (size_t)(row0 + i) * N + col0)     = *(float4*)&acc[i][0];
        *(float4*)(C + (size_t)(row0 + i) * N + col0 + 4) = *(float4*)&acc[i][4];
    }
}

// ---------------- final: out[g,h] = bh2[h] + sum_k a[g, h*32+k] * Wh2[h*32+k] ----------------
__global__ __launch_bounds__(256) void k_heads_out(const float* __restrict__ a,
                                                   const float* __restrict__ Wh2,
                                                   const float* __restrict__ bh2,
                                                   float* __restrict__ out) {
    int i = blockIdx.x * 256 + threadIdx.x;
    if (i >= N_GRAPHS * 6) return;
    int g = i / 6, h = i % 6;
    const float* ap = a + (size_t)g * 256 + h * 32;
    const float* wp = Wh2 + h * 32;
    float s = 0.0f;
    #pragma unroll
    for (int k = 0; k < 32; k++) s = fmaf(ap[k], wp[k], s);
    out[i] = s + bh2[h];
}

extern "C" void kernel_launch(void* const* d_in, const int* in_sizes, int n_in,
                              void* d_out, int out_size, void* d_ws, size_t ws_size,
                              hipStream_t stream) {
    const float* x    = (const float*)d_in[0];
    const int*   esrc = (const int*)d_in[1];
    const int*   edst = (const int*)d_in[2];
    const int*   batch= (const int*)d_in[3];
    const float* solv = (const float*)d_in[4];
    const float* Wc1  = (const float*)d_in[5];
    const float* bc1  = (const float*)d_in[6];
    const float* Wc2  = (const float*)d_in[7];
    const float* bc2  = (const float*)d_in[8];
    const float* W1   = (const float*)d_in[9];
    const float* b1   = (const float*)d_in[10];
    const float* W2   = (const float*)d_in[11];
    const float* b2   = (const float*)d_in[12];
    const float* W3   = (const float*)d_in[13];
    const float* b3   = (const float*)d_in[14];
    const float* Wh1  = (const float*)d_in[15];
    const float* bh1  = (const float*)d_in[16];
    const float* Wh2  = (const float*)d_in[17];
    const float* bh2  = (const float*)d_in[18];
    float* out = (float*)d_out;

    // workspace layout (floats)
    float* ws   = (float*)d_ws;
    float* dinv = ws;                                  // 500000 (reserve 524288)
    float* bufA = ws + 524288;                         // 64,000,000
    float* bufB = bufA + 64000000;                     // 64,000,000
    float* zpad = bufB + 64000000;                     // 16384*80
    float* w1pad= zpad + (size_t)N_GRAPHS * 80;        // 80*2048
    float* whcat= w1pad + 80 * 2048;                   // 128*256
    float* bh1p = whcat + 128 * 256;                   // 256
    float* agg2 = bufA + 32000000;                     // [500000,64] second half of bufA
    float* z1   = bufA;                                // [16384,2048]
    float* z2   = bufB;                                // [16384,1024]
    float* z3   = bufA;                                // [16384,128]
    float* abuf = bufB;                                // [16384,256]

    // 1) degree -> dinv
    k_init_deg<<<(N_NODES + 255) / 256, 256, 0, stream>>>(dinv);
    k_count  <<<(N_EDGES + 255) / 256, 256, 0, stream>>>(edst, dinv);
    k_rsqrt  <<<(N_NODES + 255) / 256, 256, 0, stream>>>(dinv);

    // 2) conv1: hpre = x @ Wc1 -> bufA
    k_rowgemm<131, 128, false><<<N_NODES / 8, 256, 0, stream>>>(x, Wc1, bufA);
    // 3) agg1 = dinv^2*hpre + bc1 -> bufB; scatter edges
    k_init_agg<128><<<(N_NODES * 128 / 4 + 255) / 256, 256, 0, stream>>>(bufA, dinv, bc1, bufB);
    k_scatter<128><<<(N_EDGES * 64) / 256, 256, 0, stream>>>(esrc, edst, dinv, bufA, bufB);

    // 4) conv2: h2pre = relu(agg1) @ Wc2 -> bufA[0:32M]
    k_rowgemm<128, 64, true><<<N_NODES / 16, 256, 0, stream>>>(bufB, Wc2, bufA);
    // 5) agg2 = dinv^2*h2pre + bc2 -> bufA[32M:]; scatter edges
    k_init_agg<64><<<(N_NODES * 64 / 4 + 255) / 256, 256, 0, stream>>>(bufA, dinv, bc2, agg2);
    k_scatter<64><<<(N_EDGES * 64) / 256, 256, 0, stream>>>(esrc, edst, dinv, bufA, agg2);

    // 6) pool into zpad (cols 0..63), solvent in cols 64..74, zeros elsewhere
    k_zpad_init<<<(N_GRAPHS * 80 + 255) / 256, 256, 0, stream>>>(solv, zpad);
    k_pool<<<(N_NODES * 64) / 256, 256, 0, stream>>>(agg2, batch, zpad);

    // 7) MLP
    k_w1pad<<<(80 * 2048) / 256, 256, 0, stream>>>(W1, w1pad);
    k_gemm<true><<<dim3(2048 / 128, N_GRAPHS / 128), 256, 0, stream>>>(zpad, w1pad, b1, z1, N_GRAPHS, 2048, 80);
    k_gemm<true><<<dim3(1024 / 128, N_GRAPHS / 128), 256, 0, stream>>>(z1, W2, b2, z2, N_GRAPHS, 1024, 2048);
    k_gemm<true><<<dim3(128 / 128, N_GRAPHS / 128), 256, 0, stream>>>(z2, W3, b3, z3, N_GRAPHS, 128, 1024);

    // 8) heads
    k_whcat<<<(128 * 256) / 256, 256, 0, stream>>>(Wh1, whcat);
    k_bh1pad<<<1, 256, 0, stream>>>(bh1, bh1p);
    k_gemm<true><<<dim3(256 / 128, N_GRAPHS / 128), 256, 0, stream>>>(z3, whcat, bh1p, abuf, N_GRAPHS, 256, 128);
    k_heads_out<<<(N_GRAPHS * 6 + 255) / 256, 256, 0, stream>>>(abuf, Wh2, bh2, out);
}

// Round 2
// 3435.617 us; speedup vs baseline: 1.4548x; 1.4548x over previous
//
#include <hip/hip_runtime.h>

#define N_NODES 500000
#define N_EDGES 2000000
#define N_GRAPHS 16384

#define SCAN_ELEMS 2048
#define SCAN_NBLK ((N_NODES + SCAN_ELEMS - 1) / SCAN_ELEMS)   // 245

// ---------------- CSR build ----------------
__global__ __launch_bounds__(256) void k_zero_counts(int* counts) {
    int i = blockIdx.x * 256 + threadIdx.x;
    if (i < N_NODES) counts[i] = 0;
}
__global__ __launch_bounds__(256) void k_hist(const int* __restrict__ dst, int* __restrict__ counts) {
    int e = blockIdx.x * 256 + threadIdx.x;
    if (e < N_EDGES) atomicAdd(&counts[dst[e]], 1);
}
__global__ __launch_bounds__(256) void k_scan_reduce(const int* __restrict__ counts, int* __restrict__ bsum) {
    int b = blockIdx.x, t = threadIdx.x;
    int base_i = b * SCAN_ELEMS + t * 8;
    int s = 0;
    #pragma unroll
    for (int j = 0; j < 8; j++) { int i = base_i + j; if (i < N_NODES) s += counts[i]; }
    __shared__ int sh[256];
    sh[t] = s; __syncthreads();
    for (int off = 128; off > 0; off >>= 1) { if (t < off) sh[t] += sh[t + off]; __syncthreads(); }
    if (t == 0) bsum[b] = sh[0];
}
__global__ __launch_bounds__(256) void k_scan_bsum(const int* __restrict__ bsum, int* __restrict__ boff,
                                                   int* __restrict__ row_ptr) {
    __shared__ int sh[256];
    int t = threadIdx.x;
    int v = (t < SCAN_NBLK) ? bsum[t] : 0;
    sh[t] = v; __syncthreads();
    for (int off = 1; off < 256; off <<= 1) {
        int u = (t >= off) ? sh[t - off] : 0;
        __syncthreads();
        sh[t] += u; __syncthreads();
    }
    boff[t] = sh[t] - v;                       // exclusive block offsets
    if (t == 255) row_ptr[N_NODES] = sh[255];  // total == N_EDGES
}
__global__ __launch_bounds__(256) void k_scan_final(const int* __restrict__ counts, const int* __restrict__ boff,
                                                    int* __restrict__ row_ptr, int* __restrict__ cursor,
                                                    float* __restrict__ dinv) {
    __shared__ int sh[256];
    int b = blockIdx.x, t = threadIdx.x;
    int base_i = b * SCAN_ELEMS + t * 8;
    int c[8]; int tsum = 0;
    #pragma unroll
    for (int j = 0; j < 8; j++) {
        int i = base_i + j;
        c[j] = (i < N_NODES) ? counts[i] : 0;
        tsum += c[j];
    }
    sh[t] = tsum; __syncthreads();
    for (int off = 1; off < 256; off <<= 1) {
        int u = (t >= off) ? sh[t - off] : 0;
        __syncthreads();
        sh[t] += u; __syncthreads();
    }
    int run = boff[b] + sh[t] - tsum;
    #pragma unroll
    for (int j = 0; j < 8; j++) {
        int i = base_i + j;
        if (i < N_NODES) {
            row_ptr[i] = run;
            cursor[i]  = run;
            dinv[i]    = rsqrtf((float)c[j] + 1.0f);   // deg = counts + 1 (self loop)
        }
        run += c[j];
    }
}
__global__ __launch_bounds__(256) void k_fill(const int* __restrict__ esrc, const int* __restrict__ edst,
                                              int* __restrict__ cursor, int* __restrict__ srcs) {
    int e = blockIdx.x * 256 + threadIdx.x;
    if (e >= N_EDGES) return;
    int d = edst[e];
    int pos = atomicAdd(&cursor[d], 1);
    srcs[pos] = esrc[e];
}

// ---------------- rowwise GEMM for conv layers: out[M,N] = X[M,K] @ W[K,N] ----------------
template<int K, int N, bool RELU_IN>
__global__ __launch_bounds__(256) void k_rowgemm(const float* __restrict__ X,
                                                 const float* __restrict__ W,
                                                 float* __restrict__ out) {
    constexpr int TPR = N / 4;
    constexpr int RPB = 256 / TPR;
    __shared__ float xs[RPB][K];
    const int r0 = blockIdx.x * RPB;
    for (int i = threadIdx.x; i < RPB * K; i += 256) {
        int r = i / K, k = i % K;
        float v = X[(size_t)(r0 + r) * K + k];
        xs[r][k] = RELU_IN ? fmaxf(v, 0.0f) : v;
    }
    __syncthreads();
    const int r  = threadIdx.x / TPR;
    const int c0 = (threadIdx.x % TPR) * 4;
    const int row = r0 + r;
    float4 acc = {0.f, 0.f, 0.f, 0.f};
    #pragma unroll 4
    for (int k = 0; k < K; k++) {
        float xv = xs[r][k];
        float4 w = *(const float4*)(W + (size_t)k * N + c0);
        acc.x = fmaf(xv, w.x, acc.x);
        acc.y = fmaf(xv, w.y, acc.y);
        acc.z = fmaf(xv, w.z, acc.z);
        acc.w = fmaf(xv, w.w, acc.w);
    }
    *(float4*)(out + (size_t)row * N + c0) = acc;
}

// ---------------- conv1 gather: agg[n] = dinv[n]^2*h[n] + bias + sum_e dinv[s]*dinv[n]*h[s] ----------------
// one wave per node, 64 lanes x float2 (N=128)
__global__ __launch_bounds__(256) void k_gather1(const float* __restrict__ h, const float* __restrict__ dinv,
                                                 const float* __restrict__ bias,
                                                 const int* __restrict__ row_ptr, const int* __restrict__ srcs,
                                                 float* __restrict__ agg) {
    int g = blockIdx.x * 256 + threadIdx.x;
    int n = g >> 6, lane = g & 63;
    if (n >= N_NODES) return;
    float dn = dinv[n];
    int c = lane * 2;
    float2 hv = *(const float2*)(h + (size_t)n * 128 + c);
    float s2 = dn * dn;
    float2 acc;
    acc.x = fmaf(s2, hv.x, bias[c]);
    acc.y = fmaf(s2, hv.y, bias[c + 1]);
    int e0 = row_ptr[n], e1 = row_ptr[n + 1];
    for (int e = e0; e < e1; e++) {
        int s = srcs[e];
        float nrm = dinv[s] * dn;
        float2 hs = *(const float2*)(h + (size_t)s * 128 + c);
        acc.x = fmaf(nrm, hs.x, acc.x);
        acc.y = fmaf(nrm, hs.y, acc.y);
    }
    *(float2*)(agg + (size_t)n * 128 + c) = acc;
}

// ---------------- conv2 gather fused with global sum pool into zpad cols 0..63 ----------------
__global__ __launch_bounds__(256) void k_gather2_pool(const float* __restrict__ h, const float* __restrict__ dinv,
                                                      const float* __restrict__ bias,
                                                      const int* __restrict__ row_ptr, const int* __restrict__ srcs,
                                                      const int* __restrict__ batch,
                                                      float* __restrict__ zpad) {
    int g = blockIdx.x * 256 + threadIdx.x;
    int n = g >> 6, lane = g & 63;
    if (n >= N_NODES) return;
    float dn = dinv[n];
    float hv = h[(size_t)n * 64 + lane];
    float acc = fmaf(dn * dn, hv, bias[lane]);
    int e0 = row_ptr[n], e1 = row_ptr[n + 1];
    for (int e = e0; e < e1; e++) {
        int s = srcs[e];
        acc = fmaf(dinv[s] * dn, h[(size_t)s * 64 + lane], acc);
    }
    atomicAdd(&zpad[(size_t)batch[n] * 80 + lane], acc);
}

// ---------------- zpad init: [G, 80] = [zeros(0..63) | solvent(64..74) | zeros] ----------------
__global__ __launch_bounds__(256) void k_zpad_init(const float* __restrict__ solv, float* __restrict__ zpad) {
    int i = blockIdx.x * 256 + threadIdx.x;
    if (i >= N_GRAPHS * 80) return;
    int g = i / 80, c = i % 80;
    float v = 0.0f;
    if (c >= 64 && c < 75) v = solv[g * 11 + (c - 64)];
    zpad[i] = v;
}

// ---------------- W1 pad 75->80 rows ----------------
__global__ __launch_bounds__(256) void k_w1pad(const float* __restrict__ W1, float* __restrict__ w1pad) {
    int i = blockIdx.x * 256 + threadIdx.x;
    if (i >= 80 * 2048) return;
    int r = i / 2048, c = i % 2048;
    w1pad[i] = (r < 75) ? W1[r * 2048 + c] : 0.0f;
}

// ---------------- heads weight concat, padded to 256 cols ----------------
__global__ __launch_bounds__(256) void k_whcat(const float* __restrict__ Wh1, float* __restrict__ whcat) {
    int i = blockIdx.x * 256 + threadIdx.x;
    if (i >= 128 * 256) return;
    int f = i / 256, c = i % 256;
    float v = 0.0f;
    if (c < 192) {
        int h = c / 32, k = c & 31;
        v = Wh1[h * 128 * 32 + f * 32 + k];
    }
    whcat[i] = v;
}
__global__ __launch_bounds__(256) void k_bh1pad(const float* __restrict__ bh1, float* __restrict__ bh1pad) {
    int i = threadIdx.x;
    bh1pad[i] = (i < 192) ? bh1[i] : 0.0f;
}

// ---------------- tiled fp32 GEMM: C[M,N] = act(A[M,K] @ B[K,N] + bias) ----------------
template<bool RELU>
__global__ __launch_bounds__(256) void k_gemm(const float* __restrict__ A,
                                              const float* __restrict__ B,
                                              const float* __restrict__ bias,
                                              float* __restrict__ C,
                                              int M, int N, int K) {
    __shared__ float As[8][132];
    __shared__ float Bs[8][132];
    const int tid = threadIdx.x;
    const int bm = blockIdx.y, bn = blockIdx.x;
    const int tr = (tid >> 4) << 3;
    const int tc = (tid & 15) << 3;
    float acc[8][8] = {};
    const float* Ab = A + (size_t)bm * 128 * K;
    const float* Bb = B + (size_t)bn * 128;
    const int la_r = tid >> 1, la_c = (tid & 1) << 2;
    const int lb_r = tid >> 5, lb_c = (tid & 31) << 2;
    for (int k0 = 0; k0 < K; k0 += 8) {
        float4 a4 = *(const float4*)(Ab + (size_t)la_r * K + k0 + la_c);
        float4 b4 = *(const float4*)(Bb + (size_t)(k0 + lb_r) * N + lb_c);
        __syncthreads();
        As[la_c + 0][la_r] = a4.x;
        As[la_c + 1][la_r] = a4.y;
        As[la_c + 2][la_r] = a4.z;
        As[la_c + 3][la_r] = a4.w;
        *(float4*)&Bs[lb_r][lb_c] = b4;
        __syncthreads();
        #pragma unroll
        for (int k = 0; k < 8; k++) {
            float a[8], b[8];
            *(float4*)&a[0] = *(const float4*)&As[k][tr];
            *(float4*)&a[4] = *(const float4*)&As[k][tr + 4];
            *(float4*)&b[0] = *(const float4*)&Bs[k][tc];
            *(float4*)&b[4] = *(const float4*)&Bs[k][tc + 4];
            #pragma unroll
            for (int i = 0; i < 8; i++)
                #pragma unroll
                for (int j = 0; j < 8; j++)
                    acc[i][j] = fmaf(a[i], b[j], acc[i][j]);
        }
    }
    const int row0 = bm * 128 + tr, col0 = bn * 128 + tc;
    #pragma unroll
    for (int i = 0; i < 8; i++) {
        #pragma unroll
        for (int j = 0; j < 8; j++) {
            float v = acc[i][j] + bias[col0 + j];
            if (RELU) v = fmaxf(v, 0.0f);
            acc[i][j] = v;
        }
        *(float4*)(C + (size_t)(row0 + i) * N + col0)     = *(float4*)&acc[i][0];
        *(float4*)(C + (size_t)(row0 + i) * N + col0 + 4) = *(float4*)&acc[i][4];
    }
}

// ---------------- final heads reduce ----------------
__global__ __launch_bounds__(256) void k_heads_out(const float* __restrict__ a,
                                                   const float* __restrict__ Wh2,
                                                   const float* __restrict__ bh2,
                                                   float* __restrict__ out) {
    int i = blockIdx.x * 256 + threadIdx.x;
    if (i >= N_GRAPHS * 6) return;
    int g = i / 6, h = i % 6;
    const float* ap = a + (size_t)g * 256 + h * 32;
    const float* wp = Wh2 + h * 32;
    float s = 0.0f;
    #pragma unroll
    for (int k = 0; k < 32; k++) s = fmaf(ap[k], wp[k], s);
    out[i] = s + bh2[h];
}

extern "C" void kernel_launch(void* const* d_in, const int* in_sizes, int n_in,
                              void* d_out, int out_size, void* d_ws, size_t ws_size,
                              hipStream_t stream) {
    const float* x    = (const float*)d_in[0];
    const int*   esrc = (const int*)d_in[1];
    const int*   edst = (const int*)d_in[2];
    const int*   batch= (const int*)d_in[3];
    const float* solv = (const float*)d_in[4];
    const float* Wc1  = (const float*)d_in[5];
    const float* bc1  = (const float*)d_in[6];
    const float* Wc2  = (const float*)d_in[7];
    const float* bc2  = (const float*)d_in[8];
    const float* W1   = (const float*)d_in[9];
    const float* b1   = (const float*)d_in[10];
    const float* W2   = (const float*)d_in[11];
    const float* b2   = (const float*)d_in[12];
    const float* W3   = (const float*)d_in[13];
    const float* b3   = (const float*)d_in[14];
    const float* Wh1  = (const float*)d_in[15];
    const float* bh1  = (const float*)d_in[16];
    const float* Wh2  = (const float*)d_in[17];
    const float* bh2  = (const float*)d_in[18];
    float* out = (float*)d_out;

    // workspace layout
    float* ws    = (float*)d_ws;
    float* bufA  = ws;                         // 64,000,000 f
    float* bufB  = bufA + 64000000;            // 64,000,000 f
    float* dinv  = bufB + 64000000;            // 524,288 f
    float* zpad  = dinv + 524288;              // 1,310,720 f
    float* w1pad = zpad + (size_t)N_GRAPHS * 80;  // 163,840 f
    float* whcat = w1pad + 80 * 2048;          // 32,768 f
    float* bh1p  = whcat + 128 * 256;          // 256 f
    int* counts  = (int*)(bh1p + 256);         // 500,000
    int* row_ptr = counts + N_NODES;           // 500,001 (pad 500,224)
    int* cursor  = row_ptr + 500224;           // 500,000
    int* srcs    = cursor + N_NODES;           // 2,000,000
    int* bsum    = srcs + N_EDGES;             // 256
    int* boff    = bsum + 256;                 // 256

    // 1) CSR build + dinv
    k_zero_counts<<<(N_NODES + 255) / 256, 256, 0, stream>>>(counts);
    k_hist<<<(N_EDGES + 255) / 256, 256, 0, stream>>>(edst, counts);
    k_scan_reduce<<<SCAN_NBLK, 256, 0, stream>>>(counts, bsum);
    k_scan_bsum<<<1, 256, 0, stream>>>(bsum, boff, row_ptr);
    k_scan_final<<<SCAN_NBLK, 256, 0, stream>>>(counts, boff, row_ptr, cursor, dinv);
    k_fill<<<(N_EDGES + 255) / 256, 256, 0, stream>>>(esrc, edst, cursor, srcs);

    // 2) conv1: hpre = x @ Wc1 -> bufA ; gather -> bufB
    k_rowgemm<131, 128, false><<<N_NODES / 8, 256, 0, stream>>>(x, Wc1, bufA);
    k_gather1<<<(N_NODES * 64) / 256, 256, 0, stream>>>(bufA, dinv, bc1, row_ptr, srcs, bufB);

    // 3) conv2: h2pre = relu(agg1) @ Wc2 -> bufA[0:32M] ; gather+pool -> zpad
    k_rowgemm<128, 64, true><<<N_NODES / 16, 256, 0, stream>>>(bufB, Wc2, bufA);
    k_zpad_init<<<(N_GRAPHS * 80 + 255) / 256, 256, 0, stream>>>(solv, zpad);
    k_gather2_pool<<<(N_NODES * 64) / 256, 256, 0, stream>>>(bufA, dinv, bc2, row_ptr, srcs, batch, zpad);

    // 4) MLP
    k_w1pad<<<(80 * 2048) / 256, 256, 0, stream>>>(W1, w1pad);
    float* z1 = bufB;   // [16384,2048]
    float* z2 = bufA;   // [16384,1024]
    float* z3 = bufB;   // [16384,128]
    float* ab = bufA;   // [16384,256]
    k_gemm<true><<<dim3(2048 / 128, N_GRAPHS / 128), 256, 0, stream>>>(zpad, w1pad, b1, z1, N_GRAPHS, 2048, 80);
    k_gemm<true><<<dim3(1024 / 128, N_GRAPHS / 128), 256, 0, stream>>>(z1, W2, b2, z2, N_GRAPHS, 1024, 2048);
    k_gemm<true><<<dim3(128 / 128, N_GRAPHS / 128), 256, 0, stream>>>(z2, W3, b3, z3, N_GRAPHS, 128, 1024);

    // 5) heads
    k_whcat<<<(128 * 256) / 256, 256, 0, stream>>>(Wh1, whcat);
    k_bh1pad<<<1, 256, 0, stream>>>(bh1, bh1p);
    k_gemm<true><<<dim3(256 / 128, N_GRAPHS / 128), 256, 0, stream>>>(z3, whcat, bh1p, ab, N_GRAPHS, 256, 128);
    k_heads_out<<<(N_GRAPHS * 6 + 255) / 256, 256, 0, stream>>>(ab, Wh2, bh2, out);
}

// Round 3
// 2427.743 us; speedup vs baseline: 2.0588x; 1.4151x over previous
//
#include <hip/hip_runtime.h>

#define N_NODES 500000
#define N_EDGES 2000000
#define N_GRAPHS 16384

#define SCAN_ELEMS 2048
#define SCAN_NBLK ((N_NODES + SCAN_ELEMS - 1) / SCAN_ELEMS)   // 245

// ---------------- CSR build ----------------
__global__ __launch_bounds__(256) void k_zero_counts(int* counts) {
    int i = blockIdx.x * 256 + threadIdx.x;
    if (i < N_NODES) counts[i] = 0;
}
__global__ __launch_bounds__(256) void k_hist(const int* __restrict__ dst, int* __restrict__ counts) {
    int e = blockIdx.x * 256 + threadIdx.x;
    if (e < N_EDGES) atomicAdd(&counts[dst[e]], 1);
}
__global__ __launch_bounds__(256) void k_scan_reduce(const int* __restrict__ counts, int* __restrict__ bsum) {
    int b = blockIdx.x, t = threadIdx.x;
    int base_i = b * SCAN_ELEMS + t * 8;
    int s = 0;
    #pragma unroll
    for (int j = 0; j < 8; j++) { int i = base_i + j; if (i < N_NODES) s += counts[i]; }
    __shared__ int sh[256];
    sh[t] = s; __syncthreads();
    for (int off = 128; off > 0; off >>= 1) { if (t < off) sh[t] += sh[t + off]; __syncthreads(); }
    if (t == 0) bsum[b] = sh[0];
}
__global__ __launch_bounds__(256) void k_scan_bsum(const int* __restrict__ bsum, int* __restrict__ boff,
                                                   int* __restrict__ row_ptr) {
    __shared__ int sh[256];
    int t = threadIdx.x;
    int v = (t < SCAN_NBLK) ? bsum[t] : 0;
    sh[t] = v; __syncthreads();
    for (int off = 1; off < 256; off <<= 1) {
        int u = (t >= off) ? sh[t - off] : 0;
        __syncthreads();
        sh[t] += u; __syncthreads();
    }
    boff[t] = sh[t] - v;
    if (t == 255) row_ptr[N_NODES] = sh[255];
}
__global__ __launch_bounds__(256) void k_scan_final(const int* __restrict__ counts, const int* __restrict__ boff,
                                                    int* __restrict__ row_ptr, int* __restrict__ cursor,
                                                    float* __restrict__ dinv) {
    __shared__ int sh[256];
    int b = blockIdx.x, t = threadIdx.x;
    int base_i = b * SCAN_ELEMS + t * 8;
    int c[8]; int tsum = 0;
    #pragma unroll
    for (int j = 0; j < 8; j++) {
        int i = base_i + j;
        c[j] = (i < N_NODES) ? counts[i] : 0;
        tsum += c[j];
    }
    sh[t] = tsum; __syncthreads();
    for (int off = 1; off < 256; off <<= 1) {
        int u = (t >= off) ? sh[t - off] : 0;
        __syncthreads();
        sh[t] += u; __syncthreads();
    }
    int run = boff[b] + sh[t] - tsum;
    #pragma unroll
    for (int j = 0; j < 8; j++) {
        int i = base_i + j;
        if (i < N_NODES) {
            row_ptr[i] = run;
            cursor[i]  = run;
            dinv[i]    = rsqrtf((float)c[j] + 1.0f);
        }
        run += c[j];
    }
}
__global__ __launch_bounds__(256) void k_fill(const int* __restrict__ esrc, const int* __restrict__ edst,
                                              int* __restrict__ cursor, int* __restrict__ srcs) {
    int e = blockIdx.x * 256 + threadIdx.x;
    if (e >= N_EDGES) return;
    int d = edst[e];
    int pos = atomicAdd(&cursor[d], 1);
    srcs[pos] = esrc[e];
}
// graph segment starts from sorted batch_index
__global__ __launch_bounds__(256) void k_gstart(const int* __restrict__ batch, int* __restrict__ gstart) {
    int g = blockIdx.x * 256 + threadIdx.x;
    if (g > N_GRAPHS) return;
    if (g == N_GRAPHS) { gstart[g] = N_NODES; return; }
    int lo = 0, hi = N_NODES;
    while (lo < hi) { int mid = (lo + hi) >> 1; if (batch[mid] < g) lo = mid + 1; else hi = mid; }
    gstart[g] = lo;
}

// ---------------- conv1 tiled GEMM: C[M,128] = A[M,131] @ B[131,128] ----------------
template<int KTOT>
__global__ __launch_bounds__(256) void k_gemm_conv1(const float* __restrict__ A,
                                                    const float* __restrict__ B,
                                                    float* __restrict__ C, int Mreal) {
    __shared__ float As[8][132];
    __shared__ float Bs[8][132];
    const int tid = threadIdx.x;
    const int bm = blockIdx.x;
    const int tr = (tid >> 4) << 3;
    const int tc = (tid & 15) << 3;
    float acc[8][8] = {};
    const int la_r = tid >> 1, la_c = (tid & 1) << 2;
    const int lb_r = tid >> 5, lb_c = (tid & 31) << 2;
    const int arow = min(bm * 128 + la_r, Mreal - 1);
    const float* Ap = A + (size_t)arow * KTOT + la_c;
    constexpr int KMAIN = (KTOT / 8) * 8;
    for (int k0 = 0; k0 < KMAIN; k0 += 8) {
        float4 a4 = *(const float4*)(Ap + k0);
        float4 b4 = *(const float4*)(B + (size_t)(k0 + lb_r) * 128 + lb_c);
        __syncthreads();
        As[la_c + 0][la_r] = a4.x;
        As[la_c + 1][la_r] = a4.y;
        As[la_c + 2][la_r] = a4.z;
        As[la_c + 3][la_r] = a4.w;
        *(float4*)&Bs[lb_r][lb_c] = b4;
        __syncthreads();
        #pragma unroll
        for (int k = 0; k < 8; k++) {
            float a[8], b[8];
            *(float4*)&a[0] = *(const float4*)&As[k][tr];
            *(float4*)&a[4] = *(const float4*)&As[k][tr + 4];
            *(float4*)&b[0] = *(const float4*)&Bs[k][tc];
            *(float4*)&b[4] = *(const float4*)&Bs[k][tc + 4];
            #pragma unroll
            for (int i = 0; i < 8; i++)
                #pragma unroll
                for (int j = 0; j < 8; j++)
                    acc[i][j] = fmaf(a[i], b[j], acc[i][j]);
        }
    }
    if (KTOT % 8 != 0) {
        constexpr int k0 = KMAIN;
        float av[4];
        #pragma unroll
        for (int j = 0; j < 4; j++) av[j] = (k0 + la_c + j < KTOT) ? Ap[k0 + j] : 0.0f;
        float4 b4 = {0.f, 0.f, 0.f, 0.f};
        if (k0 + lb_r < KTOT) b4 = *(const float4*)(B + (size_t)(k0 + lb_r) * 128 + lb_c);
        __syncthreads();
        As[la_c + 0][la_r] = av[0];
        As[la_c + 1][la_r] = av[1];
        As[la_c + 2][la_r] = av[2];
        As[la_c + 3][la_r] = av[3];
        *(float4*)&Bs[lb_r][lb_c] = b4;
        __syncthreads();
        #pragma unroll
        for (int k = 0; k < 8; k++) {
            float a[8], b[8];
            *(float4*)&a[0] = *(const float4*)&As[k][tr];
            *(float4*)&a[4] = *(const float4*)&As[k][tr + 4];
            *(float4*)&b[0] = *(const float4*)&Bs[k][tc];
            *(float4*)&b[4] = *(const float4*)&Bs[k][tc + 4];
            #pragma unroll
            for (int i = 0; i < 8; i++)
                #pragma unroll
                for (int j = 0; j < 8; j++)
                    acc[i][j] = fmaf(a[i], b[j], acc[i][j]);
        }
    }
    const int row0 = bm * 128 + tr;
    #pragma unroll
    for (int i = 0; i < 8; i++) {
        if (row0 + i < Mreal) {
            *(float4*)(C + (size_t)(row0 + i) * 128 + tc)     = *(float4*)&acc[i][0];
            *(float4*)(C + (size_t)(row0 + i) * 128 + tc + 4) = *(float4*)&acc[i][4];
        }
    }
}

// ---------------- conv1 gather: agg1[n] = dinv[n]^2*h[n] + bc1 + sum_e dinv[s]*dinv[n]*h[s] ----------------
__global__ __launch_bounds__(256) void k_gather1(const float* __restrict__ h, const float* __restrict__ dinv,
                                                 const float* __restrict__ bias,
                                                 const int* __restrict__ row_ptr, const int* __restrict__ srcs,
                                                 float* __restrict__ agg) {
    int g = blockIdx.x * 256 + threadIdx.x;
    int n = g >> 6, lane = g & 63;
    if (n >= N_NODES) return;
    float dn = dinv[n];
    int c = lane * 2;
    float2 hv = *(const float2*)(h + (size_t)n * 128 + c);
    float s2 = dn * dn;
    float2 acc;
    acc.x = fmaf(s2, hv.x, bias[c]);
    acc.y = fmaf(s2, hv.y, bias[c + 1]);
    int e0 = row_ptr[n], e1 = row_ptr[n + 1];
    for (int e = e0; e < e1; e++) {
        int s = srcs[e];
        float nrm = dinv[s] * dn;
        float2 hs = *(const float2*)(h + (size_t)s * 128 + c);
        acc.x = fmaf(nrm, hs.x, acc.x);
        acc.y = fmaf(nrm, hs.y, acc.y);
    }
    *(float2*)(agg + (size_t)n * 128 + c) = acc;
}

// ---------------- conv2 aggregation on relu(agg1): ah[n] = dinv^2*relu + sum dinv*dinv*relu ----------------
__global__ __launch_bounds__(256) void k_gather2(const float* __restrict__ h, const float* __restrict__ dinv,
                                                 const int* __restrict__ row_ptr, const int* __restrict__ srcs,
                                                 float* __restrict__ ah) {
    int g = blockIdx.x * 256 + threadIdx.x;
    int n = g >> 6, lane = g & 63;
    if (n >= N_NODES) return;
    float dn = dinv[n];
    int c = lane * 2;
    float2 hv = *(const float2*)(h + (size_t)n * 128 + c);
    float s2 = dn * dn;
    float2 acc;
    acc.x = s2 * fmaxf(hv.x, 0.0f);
    acc.y = s2 * fmaxf(hv.y, 0.0f);
    int e0 = row_ptr[n], e1 = row_ptr[n + 1];
    for (int e = e0; e < e1; e++) {
        int s = srcs[e];
        float nrm = dinv[s] * dn;
        float2 hs = *(const float2*)(h + (size_t)s * 128 + c);
        acc.x = fmaf(nrm, fmaxf(hs.x, 0.0f), acc.x);
        acc.y = fmaf(nrm, fmaxf(hs.y, 0.0f), acc.y);
    }
    *(float2*)(ah + (size_t)n * 128 + c) = acc;
}

// ---------------- segmented pool: P[g] = sum rows gstart[g]..gstart[g+1] of ah ----------------
__global__ __launch_bounds__(256) void k_pool_seg(const float* __restrict__ ah, const int* __restrict__ gstart,
                                                  float* __restrict__ P, int* __restrict__ gcnt) {
    int g = blockIdx.x;
    int s = gstart[g], e = gstart[g + 1];
    int t = threadIdx.x;
    int c = t & 127, rr = t >> 7;
    float acc = 0.0f;
    for (int r = s + rr; r < e; r += 2) acc += ah[(size_t)r * 128 + c];
    __shared__ float sh[256];
    sh[t] = acc; __syncthreads();
    if (t < 128) P[(size_t)g * 128 + t] = sh[t] + sh[t + 128];
    if (t == 0) gcnt[g] = e - s;
}

// ---------------- zpad build: cols 0..63 = P@Wc2 + cnt*bc2 ; 64..74 = solv ; 75..79 = 0 ----------------
__global__ __launch_bounds__(128) void k_zg(const float* __restrict__ P, const int* __restrict__ gcnt,
                                            const float* __restrict__ Wc2, const float* __restrict__ bc2,
                                            const float* __restrict__ solv, float* __restrict__ zpad) {
    int g = blockIdx.x; int c = threadIdx.x;
    if (c >= 80) return;
    float v = 0.0f;
    if (c < 64) {
        const float* pr = P + (size_t)g * 128;
        float s = 0.0f;
        #pragma unroll 8
        for (int k = 0; k < 128; k++) s = fmaf(pr[k], Wc2[k * 64 + c], s);
        v = s + (float)gcnt[g] * bc2[c];
    } else if (c < 75) {
        v = solv[g * 11 + (c - 64)];
    }
    zpad[(size_t)g * 80 + c] = v;
}

// ---------------- W1 pad 75->80 rows ----------------
__global__ __launch_bounds__(256) void k_w1pad(const float* __restrict__ W1, float* __restrict__ w1pad) {
    int i = blockIdx.x * 256 + threadIdx.x;
    if (i >= 80 * 2048) return;
    int r = i / 2048, c = i % 2048;
    w1pad[i] = (r < 75) ? W1[r * 2048 + c] : 0.0f;
}

// ---------------- heads weight concat, padded to 256 cols ----------------
__global__ __launch_bounds__(256) void k_whcat(const float* __restrict__ Wh1, float* __restrict__ whcat) {
    int i = blockIdx.x * 256 + threadIdx.x;
    if (i >= 128 * 256) return;
    int f = i / 256, c = i % 256;
    float v = 0.0f;
    if (c < 192) {
        int h = c / 32, k = c & 31;
        v = Wh1[h * 128 * 32 + f * 32 + k];
    }
    whcat[i] = v;
}
__global__ __launch_bounds__(256) void k_bh1pad(const float* __restrict__ bh1, float* __restrict__ bh1pad) {
    int i = threadIdx.x;
    bh1pad[i] = (i < 192) ? bh1[i] : 0.0f;
}

// ---------------- tiled fp32 GEMM: C[M,N] = act(A[M,K] @ B[K,N] + bias) ----------------
template<bool RELU>
__global__ __launch_bounds__(256) void k_gemm(const float* __restrict__ A,
                                              const float* __restrict__ B,
                                              const float* __restrict__ bias,
                                              float* __restrict__ C,
                                              int M, int N, int K) {
    __shared__ float As[8][132];
    __shared__ float Bs[8][132];
    const int tid = threadIdx.x;
    const int bm = blockIdx.y, bn = blockIdx.x;
    const int tr = (tid >> 4) << 3;
    const int tc = (tid & 15) << 3;
    float acc[8][8] = {};
    const float* Ab = A + (size_t)bm * 128 * K;
    const float* Bb = B + (size_t)bn * 128;
    const int la_r = tid >> 1, la_c = (tid & 1) << 2;
    const int lb_r = tid >> 5, lb_c = (tid & 31) << 2;
    for (int k0 = 0; k0 < K; k0 += 8) {
        float4 a4 = *(const float4*)(Ab + (size_t)la_r * K + k0 + la_c);
        float4 b4 = *(const float4*)(Bb + (size_t)(k0 + lb_r) * N + lb_c);
        __syncthreads();
        As[la_c + 0][la_r] = a4.x;
        As[la_c + 1][la_r] = a4.y;
        As[la_c + 2][la_r] = a4.z;
        As[la_c + 3][la_r] = a4.w;
        *(float4*)&Bs[lb_r][lb_c] = b4;
        __syncthreads();
        #pragma unroll
        for (int k = 0; k < 8; k++) {
            float a[8], b[8];
            *(float4*)&a[0] = *(const float4*)&As[k][tr];
            *(float4*)&a[4] = *(const float4*)&As[k][tr + 4];
            *(float4*)&b[0] = *(const float4*)&Bs[k][tc];
            *(float4*)&b[4] = *(const float4*)&Bs[k][tc + 4];
            #pragma unroll
            for (int i = 0; i < 8; i++)
                #pragma unroll
                for (int j = 0; j < 8; j++)
                    acc[i][j] = fmaf(a[i], b[j], acc[i][j]);
        }
    }
    const int row0 = bm * 128 + tr, col0 = bn * 128 + tc;
    #pragma unroll
    for (int i = 0; i < 8; i++) {
        #pragma unroll
        for (int j = 0; j < 8; j++) {
            float v = acc[i][j] + bias[col0 + j];
            if (RELU) v = fmaxf(v, 0.0f);
            acc[i][j] = v;
        }
        *(float4*)(C + (size_t)(row0 + i) * N + col0)     = *(float4*)&acc[i][0];
        *(float4*)(C + (size_t)(row0 + i) * N + col0 + 4) = *(float4*)&acc[i][4];
    }
}

// ---------------- final heads reduce ----------------
__global__ __launch_bounds__(256) void k_heads_out(const float* __restrict__ a,
                                                   const float* __restrict__ Wh2,
                                                   const float* __restrict__ bh2,
                                                   float* __restrict__ out) {
    int i = blockIdx.x * 256 + threadIdx.x;
    if (i >= N_GRAPHS * 6) return;
    int g = i / 6, h = i % 6;
    const float* ap = a + (size_t)g * 256 + h * 32;
    const float* wp = Wh2 + h * 32;
    float s = 0.0f;
    #pragma unroll
    for (int k = 0; k < 32; k++) s = fmaf(ap[k], wp[k], s);
    out[i] = s + bh2[h];
}

extern "C" void kernel_launch(void* const* d_in, const int* in_sizes, int n_in,
                              void* d_out, int out_size, void* d_ws, size_t ws_size,
                              hipStream_t stream) {
    const float* x    = (const float*)d_in[0];
    const int*   esrc = (const int*)d_in[1];
    const int*   edst = (const int*)d_in[2];
    const int*   batch= (const int*)d_in[3];
    const float* solv = (const float*)d_in[4];
    const float* Wc1  = (const float*)d_in[5];
    const float* bc1  = (const float*)d_in[6];
    const float* Wc2  = (const float*)d_in[7];
    const float* bc2  = (const float*)d_in[8];
    const float* W1   = (const float*)d_in[9];
    const float* b1   = (const float*)d_in[10];
    const float* W2   = (const float*)d_in[11];
    const float* b2   = (const float*)d_in[12];
    const float* W3   = (const float*)d_in[13];
    const float* b3   = (const float*)d_in[14];
    const float* Wh1  = (const float*)d_in[15];
    const float* bh1  = (const float*)d_in[16];
    const float* Wh2  = (const float*)d_in[17];
    const float* bh2  = (const float*)d_in[18];
    float* out = (float*)d_out;

    // workspace layout
    float* ws    = (float*)d_ws;
    float* bufA  = ws;                             // 64,000,000 f
    float* bufB  = bufA + 64000000;                // 64,000,000 f
    float* dinv  = bufB + 64000000;                // 524,288 f
    float* zpad  = dinv + 524288;                  // 1,310,720 f
    float* w1pad = zpad + (size_t)N_GRAPHS * 80;   // 163,840 f
    float* whcat = w1pad + 80 * 2048;              // 32,768 f
    float* bh1p  = whcat + 128 * 256;              // 256 f
    int* counts  = (int*)(bh1p + 256);             // 500,000
    int* row_ptr = counts + N_NODES;               // 500,224
    int* cursor  = row_ptr + 500224;               // 500,000
    int* srcs    = cursor + N_NODES;               // 2,000,000
    int* bsum    = srcs + N_EDGES;                 // 256
    int* boff    = bsum + 256;                     // 256
    int* gstart  = boff + 256;                     // 16,640
    int* gcnt    = gstart + 16640;                 // 16,384
    float* P     = bufB + 61902848;                // 2,097,152 f (lives in dead agg1 tail)

    // 1) CSR build + dinv + graph segments
    k_zero_counts<<<(N_NODES + 255) / 256, 256, 0, stream>>>(counts);
    k_hist<<<(N_EDGES + 255) / 256, 256, 0, stream>>>(edst, counts);
    k_scan_reduce<<<SCAN_NBLK, 256, 0, stream>>>(counts, bsum);
    k_scan_bsum<<<1, 256, 0, stream>>>(bsum, boff, row_ptr);
    k_scan_final<<<SCAN_NBLK, 256, 0, stream>>>(counts, boff, row_ptr, cursor, dinv);
    k_fill<<<(N_EDGES + 255) / 256, 256, 0, stream>>>(esrc, edst, cursor, srcs);
    k_gstart<<<(N_GRAPHS + 256) / 256, 256, 0, stream>>>(batch, gstart);

    // 2) conv1: hpre = x @ Wc1 -> bufA ; gather -> agg1 (bufB)
    k_gemm_conv1<131><<<(N_NODES + 127) / 128, 256, 0, stream>>>(x, Wc1, bufA, N_NODES);
    k_gather1<<<(N_NODES * 64) / 256, 256, 0, stream>>>(bufA, dinv, bc1, row_ptr, srcs, bufB);

    // 3) conv2 reassociated: ah = A_hat * relu(agg1) -> bufA ; pool -> P ; zpad = [P@Wc2+cnt*bc2 | solv | 0]
    k_gather2<<<(N_NODES * 64) / 256, 256, 0, stream>>>(bufB, dinv, row_ptr, srcs, bufA);
    k_pool_seg<<<N_GRAPHS, 256, 0, stream>>>(bufA, gstart, P, gcnt);
    k_zg<<<N_GRAPHS, 128, 0, stream>>>(P, gcnt, Wc2, bc2, solv, zpad);

    // 4) MLP
    k_w1pad<<<(80 * 2048) / 256, 256, 0, stream>>>(W1, w1pad);
    float* z1 = bufB;   // [16384,2048]
    float* z2 = bufA;   // [16384,1024]
    float* z3 = bufB;   // [16384,128]
    float* ab = bufA;   // [16384,256]
    k_gemm<true><<<dim3(2048 / 128, N_GRAPHS / 128), 256, 0, stream>>>(zpad, w1pad, b1, z1, N_GRAPHS, 2048, 80);
    k_gemm<true><<<dim3(1024 / 128, N_GRAPHS / 128), 256, 0, stream>>>(z1, W2, b2, z2, N_GRAPHS, 1024, 2048);
    k_gemm<true><<<dim3(128 / 128, N_GRAPHS / 128), 256, 0, stream>>>(z2, W3, b3, z3, N_GRAPHS, 128, 1024);

    // 5) heads
    k_whcat<<<(128 * 256) / 256, 256, 0, stream>>>(Wh1, whcat);
    k_bh1pad<<<1, 256, 0, stream>>>(bh1, bh1p);
    k_gemm<true><<<dim3(256 / 128, N_GRAPHS / 128), 256, 0, stream>>>(z3, whcat, bh1p, ab, N_GRAPHS, 256, 128);
    k_heads_out<<<(N_GRAPHS * 6 + 255) / 256, 256, 0, stream>>>(ab, Wh2, bh2, out);
}

// Round 4
// 1684.740 us; speedup vs baseline: 2.9668x; 1.4410x over previous
//
#include <hip/hip_runtime.h>

#define N_NODES 500000
#define N_EDGES 2000000
#define N_GRAPHS 16384

#define SCAN_ELEMS 2048
#define SCAN_NBLK ((N_NODES + SCAN_ELEMS - 1) / SCAN_ELEMS)   // 245

typedef short bf16x8 __attribute__((ext_vector_type(8)));
typedef float f32x4 __attribute__((ext_vector_type(4)));
typedef unsigned short u16x8 __attribute__((ext_vector_type(8)));

__device__ __forceinline__ unsigned short f2bf_rne(float x) {
    unsigned int b = __float_as_uint(x);
    unsigned int r = (b + 0x7fffu + ((b >> 16) & 1u)) >> 16;
    return (unsigned short)r;
}
__device__ __forceinline__ float bf2f(unsigned short h) {
    return __uint_as_float(((unsigned int)h) << 16);
}
__device__ __forceinline__ void split_bf(float v, unsigned short& hi, unsigned short& lo) {
    hi = f2bf_rne(v);
    lo = f2bf_rne(v - bf2f(hi));
}

// ---------------- CSR build ----------------
__global__ __launch_bounds__(256) void k_zero_counts(int* counts) {
    int i = blockIdx.x * 256 + threadIdx.x;
    if (i < N_NODES) counts[i] = 0;
}
__global__ __launch_bounds__(256) void k_hist(const int* __restrict__ dst, int* __restrict__ counts) {
    int e = blockIdx.x * 256 + threadIdx.x;
    if (e < N_EDGES) atomicAdd(&counts[dst[e]], 1);
}
__global__ __launch_bounds__(256) void k_scan_reduce(const int* __restrict__ counts, int* __restrict__ bsum) {
    int b = blockIdx.x, t = threadIdx.x;
    int base_i = b * SCAN_ELEMS + t * 8;
    int s = 0;
    #pragma unroll
    for (int j = 0; j < 8; j++) { int i = base_i + j; if (i < N_NODES) s += counts[i]; }
    __shared__ int sh[256];
    sh[t] = s; __syncthreads();
    for (int off = 128; off > 0; off >>= 1) { if (t < off) sh[t] += sh[t + off]; __syncthreads(); }
    if (t == 0) bsum[b] = sh[0];
}
__global__ __launch_bounds__(256) void k_scan_bsum(const int* __restrict__ bsum, int* __restrict__ boff,
                                                   int* __restrict__ row_ptr) {
    __shared__ int sh[256];
    int t = threadIdx.x;
    int v = (t < SCAN_NBLK) ? bsum[t] : 0;
    sh[t] = v; __syncthreads();
    for (int off = 1; off < 256; off <<= 1) {
        int u = (t >= off) ? sh[t - off] : 0;
        __syncthreads();
        sh[t] += u; __syncthreads();
    }
    boff[t] = sh[t] - v;
    if (t == 255) row_ptr[N_NODES] = sh[255];
}
__global__ __launch_bounds__(256) void k_scan_final(const int* __restrict__ counts, const int* __restrict__ boff,
                                                    int* __restrict__ row_ptr, int* __restrict__ cursor,
                                                    float* __restrict__ dinv) {
    __shared__ int sh[256];
    int b = blockIdx.x, t = threadIdx.x;
    int base_i = b * SCAN_ELEMS + t * 8;
    int c[8]; int tsum = 0;
    #pragma unroll
    for (int j = 0; j < 8; j++) {
        int i = base_i + j;
        c[j] = (i < N_NODES) ? counts[i] : 0;
        tsum += c[j];
    }
    sh[t] = tsum; __syncthreads();
    for (int off = 1; off < 256; off <<= 1) {
        int u = (t >= off) ? sh[t - off] : 0;
        __syncthreads();
        sh[t] += u; __syncthreads();
    }
    int run = boff[b] + sh[t] - tsum;
    #pragma unroll
    for (int j = 0; j < 8; j++) {
        int i = base_i + j;
        if (i < N_NODES) {
            row_ptr[i] = run;
            cursor[i]  = run;
            dinv[i]    = rsqrtf((float)c[j] + 1.0f);
        }
        run += c[j];
    }
}
__global__ __launch_bounds__(256) void k_fill(const int* __restrict__ esrc, const int* __restrict__ edst,
                                              int* __restrict__ cursor, int* __restrict__ srcs) {
    int e = blockIdx.x * 256 + threadIdx.x;
    if (e >= N_EDGES) return;
    int d = edst[e];
    int pos = atomicAdd(&cursor[d], 1);
    srcs[pos] = esrc[e];
}
__global__ __launch_bounds__(256) void k_gstart(const int* __restrict__ batch, int* __restrict__ gstart) {
    int g = blockIdx.x * 256 + threadIdx.x;
    if (g > N_GRAPHS) return;
    if (g == N_GRAPHS) { gstart[g] = N_NODES; return; }
    int lo = 0, hi = N_NODES;
    while (lo < hi) { int mid = (lo + hi) >> 1; if (batch[mid] < g) lo = mid + 1; else hi = mid; }
    gstart[g] = lo;
}

// ---------------- conv1 tiled GEMM: C[M,128] = A[M,131] @ B[131,128] ----------------
template<int KTOT>
__global__ __launch_bounds__(256) void k_gemm_conv1(const float* __restrict__ A,
                                                    const float* __restrict__ B,
                                                    float* __restrict__ C, int Mreal) {
    __shared__ float As[8][132];
    __shared__ float Bs[8][132];
    const int tid = threadIdx.x;
    const int bm = blockIdx.x;
    const int tr = (tid >> 4) << 3;
    const int tc = (tid & 15) << 3;
    float acc[8][8] = {};
    const int la_r = tid >> 1, la_c = (tid & 1) << 2;
    const int lb_r = tid >> 5, lb_c = (tid & 31) << 2;
    const int arow = min(bm * 128 + la_r, Mreal - 1);
    const float* Ap = A + (size_t)arow * KTOT + la_c;
    constexpr int KMAIN = (KTOT / 8) * 8;
    for (int k0 = 0; k0 < KMAIN; k0 += 8) {
        float4 a4 = *(const float4*)(Ap + k0);
        float4 b4 = *(const float4*)(B + (size_t)(k0 + lb_r) * 128 + lb_c);
        __syncthreads();
        As[la_c + 0][la_r] = a4.x;
        As[la_c + 1][la_r] = a4.y;
        As[la_c + 2][la_r] = a4.z;
        As[la_c + 3][la_r] = a4.w;
        *(float4*)&Bs[lb_r][lb_c] = b4;
        __syncthreads();
        #pragma unroll
        for (int k = 0; k < 8; k++) {
            float a[8], b[8];
            *(float4*)&a[0] = *(const float4*)&As[k][tr];
            *(float4*)&a[4] = *(const float4*)&As[k][tr + 4];
            *(float4*)&b[0] = *(const float4*)&Bs[k][tc];
            *(float4*)&b[4] = *(const float4*)&Bs[k][tc + 4];
            #pragma unroll
            for (int i = 0; i < 8; i++)
                #pragma unroll
                for (int j = 0; j < 8; j++)
                    acc[i][j] = fmaf(a[i], b[j], acc[i][j]);
        }
    }
    if (KTOT % 8 != 0) {
        constexpr int k0 = KMAIN;
        float av[4];
        #pragma unroll
        for (int j = 0; j < 4; j++) av[j] = (k0 + la_c + j < KTOT) ? Ap[k0 + j] : 0.0f;
        float4 b4 = {0.f, 0.f, 0.f, 0.f};
        if (k0 + lb_r < KTOT) b4 = *(const float4*)(B + (size_t)(k0 + lb_r) * 128 + lb_c);
        __syncthreads();
        As[la_c + 0][la_r] = av[0];
        As[la_c + 1][la_r] = av[1];
        As[la_c + 2][la_r] = av[2];
        As[la_c + 3][la_r] = av[3];
        *(float4*)&Bs[lb_r][lb_c] = b4;
        __syncthreads();
        #pragma unroll
        for (int k = 0; k < 8; k++) {
            float a[8], b[8];
            *(float4*)&a[0] = *(const float4*)&As[k][tr];
            *(float4*)&a[4] = *(const float4*)&As[k][tr + 4];
            *(float4*)&b[0] = *(const float4*)&Bs[k][tc];
            *(float4*)&b[4] = *(const float4*)&Bs[k][tc + 4];
            #pragma unroll
            for (int i = 0; i < 8; i++)
                #pragma unroll
                for (int j = 0; j < 8; j++)
                    acc[i][j] = fmaf(a[i], b[j], acc[i][j]);
        }
    }
    const int row0 = bm * 128 + tr;
    #pragma unroll
    for (int i = 0; i < 8; i++) {
        if (row0 + i < Mreal) {
            *(float4*)(C + (size_t)(row0 + i) * 128 + tc)     = *(float4*)&acc[i][0];
            *(float4*)(C + (size_t)(row0 + i) * 128 + tc + 4) = *(float4*)&acc[i][4];
        }
    }
}

// ---------------- conv1 gather ----------------
__global__ __launch_bounds__(256) void k_gather1(const float* __restrict__ h, const float* __restrict__ dinv,
                                                 const float* __restrict__ bias,
                                                 const int* __restrict__ row_ptr, const int* __restrict__ srcs,
                                                 float* __restrict__ agg) {
    int g = blockIdx.x * 256 + threadIdx.x;
    int n = g >> 6, lane = g & 63;
    if (n >= N_NODES) return;
    float dn = dinv[n];
    int c = lane * 2;
    float2 hv = *(const float2*)(h + (size_t)n * 128 + c);
    float s2 = dn * dn;
    float2 acc;
    acc.x = fmaf(s2, hv.x, bias[c]);
    acc.y = fmaf(s2, hv.y, bias[c + 1]);
    int e0 = row_ptr[n], e1 = row_ptr[n + 1];
    for (int e = e0; e < e1; e++) {
        int s = srcs[e];
        float nrm = dinv[s] * dn;
        float2 hs = *(const float2*)(h + (size_t)s * 128 + c);
        acc.x = fmaf(nrm, hs.x, acc.x);
        acc.y = fmaf(nrm, hs.y, acc.y);
    }
    *(float2*)(agg + (size_t)n * 128 + c) = acc;
}

// ---------------- conv2 aggregation on relu(agg1) ----------------
__global__ __launch_bounds__(256) void k_gather2(const float* __restrict__ h, const float* __restrict__ dinv,
                                                 const int* __restrict__ row_ptr, const int* __restrict__ srcs,
                                                 float* __restrict__ ah) {
    int g = blockIdx.x * 256 + threadIdx.x;
    int n = g >> 6, lane = g & 63;
    if (n >= N_NODES) return;
    float dn = dinv[n];
    int c = lane * 2;
    float2 hv = *(const float2*)(h + (size_t)n * 128 + c);
    float s2 = dn * dn;
    float2 acc;
    acc.x = s2 * fmaxf(hv.x, 0.0f);
    acc.y = s2 * fmaxf(hv.y, 0.0f);
    int e0 = row_ptr[n], e1 = row_ptr[n + 1];
    for (int e = e0; e < e1; e++) {
        int s = srcs[e];
        float nrm = dinv[s] * dn;
        float2 hs = *(const float2*)(h + (size_t)s * 128 + c);
        acc.x = fmaf(nrm, fmaxf(hs.x, 0.0f), acc.x);
        acc.y = fmaf(nrm, fmaxf(hs.y, 0.0f), acc.y);
    }
    *(float2*)(ah + (size_t)n * 128 + c) = acc;
}

// ---------------- segmented pool ----------------
__global__ __launch_bounds__(256) void k_pool_seg(const float* __restrict__ ah, const int* __restrict__ gstart,
                                                  float* __restrict__ P, int* __restrict__ gcnt) {
    int g = blockIdx.x;
    int s = gstart[g], e = gstart[g + 1];
    int t = threadIdx.x;
    int c = t & 127, rr = t >> 7;
    float acc = 0.0f;
    for (int r = s + rr; r < e; r += 2) acc += ah[(size_t)r * 128 + c];
    __shared__ float sh[256];
    sh[t] = acc; __syncthreads();
    if (t < 128) P[(size_t)g * 128 + t] = sh[t] + sh[t + 128];
    if (t == 0) gcnt[g] = e - s;
}

// ---------------- zpad build ----------------
__global__ __launch_bounds__(128) void k_zg(const float* __restrict__ P, const int* __restrict__ gcnt,
                                            const float* __restrict__ Wc2, const float* __restrict__ bc2,
                                            const float* __restrict__ solv, float* __restrict__ zpad) {
    int g = blockIdx.x; int c = threadIdx.x;
    if (c >= 80) return;
    float v = 0.0f;
    if (c < 64) {
        const float* pr = P + (size_t)g * 128;
        float s = 0.0f;
        #pragma unroll 8
        for (int k = 0; k < 128; k++) s = fmaf(pr[k], Wc2[k * 64 + c], s);
        v = s + (float)gcnt[g] * bc2[c];
    } else if (c < 75) {
        v = solv[g * 11 + (c - 64)];
    }
    zpad[(size_t)g * 80 + c] = v;
}

// ---------------- W1 pad 75->80 rows ----------------
__global__ __launch_bounds__(256) void k_w1pad(const float* __restrict__ W1, float* __restrict__ w1pad) {
    int i = blockIdx.x * 256 + threadIdx.x;
    if (i >= 80 * 2048) return;
    int r = i / 2048, c = i % 2048;
    w1pad[i] = (r < 75) ? W1[r * 2048 + c] : 0.0f;
}

// ---------------- heads weight concat ----------------
__global__ __launch_bounds__(256) void k_whcat(const float* __restrict__ Wh1, float* __restrict__ whcat) {
    int i = blockIdx.x * 256 + threadIdx.x;
    if (i >= 128 * 256) return;
    int f = i / 256, c = i % 256;
    float v = 0.0f;
    if (c < 192) {
        int h = c / 32, k = c & 31;
        v = Wh1[h * 128 * 32 + f * 32 + k];
    }
    whcat[i] = v;
}
__global__ __launch_bounds__(256) void k_bh1pad(const float* __restrict__ bh1, float* __restrict__ bh1pad) {
    int i = threadIdx.x;
    bh1pad[i] = (i < 192) ? bh1[i] : 0.0f;
}

// ---------------- transpose + hi/lo split: T[c][r] = split(W[r][c]) ----------------
__global__ __launch_bounds__(256) void k_tsplit(const float* __restrict__ W, int R, int C,
                                                unsigned short* __restrict__ Th, unsigned short* __restrict__ Tl) {
    __shared__ float tile[64][65];
    int cb = blockIdx.x * 64, rb = blockIdx.y * 64;
    int tc = threadIdx.x & 63, tr4 = threadIdx.x >> 6;
    #pragma unroll 4
    for (int i = 0; i < 16; i++) {
        int r = tr4 + i * 4;
        tile[r][tc] = W[(size_t)(rb + r) * C + cb + tc];
    }
    __syncthreads();
    #pragma unroll 4
    for (int i = 0; i < 16; i++) {
        int r = tr4 + i * 4;
        float v = tile[tc][r];
        unsigned short hi, lo; split_bf(v, hi, lo);
        size_t o = (size_t)(cb + r) * R + rb + tc;
        Th[o] = hi; Tl[o] = lo;
    }
}

// ---------------- tiled fp32 GEMM: C = act(A @ B + bias); OMODE 0: fp32, 1: bf16 hi/lo ----------------
template<bool RELU, int OMODE>
__global__ __launch_bounds__(256) void k_gemm(const float* __restrict__ A,
                                              const float* __restrict__ B,
                                              const float* __restrict__ bias,
                                              float* __restrict__ C,
                                              unsigned short* __restrict__ Ch,
                                              unsigned short* __restrict__ Cl,
                                              int M, int N, int K) {
    __shared__ float As[8][132];
    __shared__ float Bs[8][132];
    const int tid = threadIdx.x;
    const int bm = blockIdx.y, bn = blockIdx.x;
    const int tr = (tid >> 4) << 3;
    const int tc = (tid & 15) << 3;
    float acc[8][8] = {};
    const float* Ab = A + (size_t)bm * 128 * K;
    const float* Bb = B + (size_t)bn * 128;
    const int la_r = tid >> 1, la_c = (tid & 1) << 2;
    const int lb_r = tid >> 5, lb_c = (tid & 31) << 2;
    for (int k0 = 0; k0 < K; k0 += 8) {
        float4 a4 = *(const float4*)(Ab + (size_t)la_r * K + k0 + la_c);
        float4 b4 = *(const float4*)(Bb + (size_t)(k0 + lb_r) * N + lb_c);
        __syncthreads();
        As[la_c + 0][la_r] = a4.x;
        As[la_c + 1][la_r] = a4.y;
        As[la_c + 2][la_r] = a4.z;
        As[la_c + 3][la_r] = a4.w;
        *(float4*)&Bs[lb_r][lb_c] = b4;
        __syncthreads();
        #pragma unroll
        for (int k = 0; k < 8; k++) {
            float a[8], b[8];
            *(float4*)&a[0] = *(const float4*)&As[k][tr];
            *(float4*)&a[4] = *(const float4*)&As[k][tr + 4];
            *(float4*)&b[0] = *(const float4*)&Bs[k][tc];
            *(float4*)&b[4] = *(const float4*)&Bs[k][tc + 4];
            #pragma unroll
            for (int i = 0; i < 8; i++)
                #pragma unroll
                for (int j = 0; j < 8; j++)
                    acc[i][j] = fmaf(a[i], b[j], acc[i][j]);
        }
    }
    const int row0 = bm * 128 + tr, col0 = bn * 128 + tc;
    #pragma unroll
    for (int i = 0; i < 8; i++) {
        if (OMODE == 0) {
            #pragma unroll
            for (int j = 0; j < 8; j++) {
                float v = acc[i][j] + bias[col0 + j];
                if (RELU) v = fmaxf(v, 0.0f);
                acc[i][j] = v;
            }
            *(float4*)(C + (size_t)(row0 + i) * N + col0)     = *(float4*)&acc[i][0];
            *(float4*)(C + (size_t)(row0 + i) * N + col0 + 4) = *(float4*)&acc[i][4];
        } else {
            u16x8 h8, l8;
            #pragma unroll
            for (int j = 0; j < 8; j++) {
                float v = acc[i][j] + bias[col0 + j];
                if (RELU) v = fmaxf(v, 0.0f);
                unsigned short hi, lo; split_bf(v, hi, lo);
                h8[j] = hi; l8[j] = lo;
            }
            *(u16x8*)(Ch + (size_t)(row0 + i) * N + col0) = h8;
            *(u16x8*)(Cl + (size_t)(row0 + i) * N + col0) = l8;
        }
    }
}

// ---------------- split-bf16 MFMA GEMM: C[M,N] = relu(A @ B^T + bias) ----------------
// A: hi/lo bf16 [M][K]; B: hi/lo bf16 [N][K] (pre-transposed). M = 16384 fixed.
// 128x128 tile, BK=64, 4 waves (2x2), 16x16x32 MFMA, XOR-swizzled LDS, global_load_lds staging.
template<int OMODE>  // 0: fp32 out, 1: bf16 hi/lo out
__global__ __launch_bounds__(256) void k_mfma_split(
        const unsigned short* __restrict__ Ah, const unsigned short* __restrict__ Al,
        const unsigned short* __restrict__ Bh, const unsigned short* __restrict__ Bl,
        const float* __restrict__ bias,
        float* __restrict__ C, unsigned short* __restrict__ Ch, unsigned short* __restrict__ Cl,
        int N, int K) {
    __shared__ short lds[32768];   // 64 KB: 4 tiles [128 rows][64 bf16], swizzled
    const int tid = threadIdx.x;
    const int w = tid >> 6, l = tid & 63;
    const int id = blockIdx.x;
    const int bm = id & 127;       // M/128 = 128; same-A blocks are 128 ids apart -> same XCD
    const int bn = id >> 7;
    // staging: wave w stages matrix w (0=Ah,1=Al,2=Bh,3=Bl)
    const unsigned short* gmat = (w == 0) ? Ah : (w == 1) ? Al : (w == 2) ? Bh : Bl;
    const size_t grow0 = (size_t)((w < 2) ? bm : bn) * 128 + (l >> 3);
    const int koffg = ((l & 7) ^ ((l >> 3) & 7)) * 8;   // ushort offset of this lane's 16B
    const int ldsw = w * 8192;                           // short index of wave's tile
    // compute mapping
    const int wm = w >> 1, wn = w & 1;
    const int lane15 = l & 15, lg = l >> 4, l7 = l & 7;
    f32x4 acc[4][4] = {};
    const int NK = K >> 6;
    for (int kt = 0; kt < NK; kt++) {
        const int k0 = kt << 6;
        __syncthreads();   // previous compute done; LDS safe to overwrite
        #pragma unroll
        for (int i = 0; i < 16; i++) {
            const unsigned short* src = gmat + (grow0 + (size_t)i * 8) * (size_t)K + k0 + koffg;
            __builtin_amdgcn_global_load_lds(
                (const __attribute__((address_space(1))) unsigned int*)src,
                (__attribute__((address_space(3))) unsigned int*)&lds[ldsw + i * 512],
                16, 0, 0);
        }
        __syncthreads();   // staging visible (vmcnt drained at barrier)
        #pragma unroll
        for (int kh = 0; kh < 2; kh++) {
            const int slot = ((kh * 4 + lg) ^ l7) * 8;
            bf16x8 ahf[4], alf[4], bhf[4], blf[4];
            #pragma unroll
            for (int m = 0; m < 4; m++) {
                int si = (wm * 64 + m * 16 + lane15) * 64 + slot;
                ahf[m] = *(const bf16x8*)&lds[si];
                alf[m] = *(const bf16x8*)&lds[8192 + si];
            }
            #pragma unroll
            for (int n = 0; n < 4; n++) {
                int si = (wn * 64 + n * 16 + lane15) * 64 + slot;
                bhf[n] = *(const bf16x8*)&lds[16384 + si];
                blf[n] = *(const bf16x8*)&lds[24576 + si];
            }
            #pragma unroll
            for (int m = 0; m < 4; m++)
                #pragma unroll
                for (int n = 0; n < 4; n++) {
                    acc[m][n] = __builtin_amdgcn_mfma_f32_16x16x32_bf16(ahf[m], bhf[n], acc[m][n], 0, 0, 0);
                    acc[m][n] = __builtin_amdgcn_mfma_f32_16x16x32_bf16(ahf[m], blf[n], acc[m][n], 0, 0, 0);
                    acc[m][n] = __builtin_amdgcn_mfma_f32_16x16x32_bf16(alf[m], bhf[n], acc[m][n], 0, 0, 0);
                }
        }
    }
    // epilogue: C row = m*16 + lg*4 + j, col = n*16 + lane15 (within wave tile)
    const int row_b = bm * 128 + wm * 64 + lg * 4;
    const int col_b = bn * 128 + wn * 64 + lane15;
    #pragma unroll
    for (int m = 0; m < 4; m++)
        #pragma unroll
        for (int n = 0; n < 4; n++) {
            int col = col_b + n * 16;
            float bv = bias[col];
            #pragma unroll
            for (int j = 0; j < 4; j++) {
                int row = row_b + m * 16 + j;
                float v = fmaxf(acc[m][n][j] + bv, 0.0f);
                size_t o = (size_t)row * N + col;
                if (OMODE == 0) {
                    C[o] = v;
                } else {
                    unsigned short hi, lo; split_bf(v, hi, lo);
                    Ch[o] = hi; Cl[o] = lo;
                }
            }
        }
}

// ---------------- final heads reduce ----------------
__global__ __launch_bounds__(256) void k_heads_out(const float* __restrict__ a,
                                                   const float* __restrict__ Wh2,
                                                   const float* __restrict__ bh2,
                                                   float* __restrict__ out) {
    int i = blockIdx.x * 256 + threadIdx.x;
    if (i >= N_GRAPHS * 6) return;
    int g = i / 6, h = i % 6;
    const float* ap = a + (size_t)g * 256 + h * 32;
    const float* wp = Wh2 + h * 32;
    float s = 0.0f;
    #pragma unroll
    for (int k = 0; k < 32; k++) s = fmaf(ap[k], wp[k], s);
    out[i] = s + bh2[h];
}

extern "C" void kernel_launch(void* const* d_in, const int* in_sizes, int n_in,
                              void* d_out, int out_size, void* d_ws, size_t ws_size,
                              hipStream_t stream) {
    const float* x    = (const float*)d_in[0];
    const int*   esrc = (const int*)d_in[1];
    const int*   edst = (const int*)d_in[2];
    const int*   batch= (const int*)d_in[3];
    const float* solv = (const float*)d_in[4];
    const float* Wc1  = (const float*)d_in[5];
    const float* bc1  = (const float*)d_in[6];
    const float* Wc2  = (const float*)d_in[7];
    const float* bc2  = (const float*)d_in[8];
    const float* W1   = (const float*)d_in[9];
    const float* b1   = (const float*)d_in[10];
    const float* W2   = (const float*)d_in[11];
    const float* b2   = (const float*)d_in[12];
    const float* W3   = (const float*)d_in[13];
    const float* b3   = (const float*)d_in[14];
    const float* Wh1  = (const float*)d_in[15];
    const float* bh1  = (const float*)d_in[16];
    const float* Wh2  = (const float*)d_in[17];
    const float* bh2  = (const float*)d_in[18];
    float* out = (float*)d_out;

    // workspace layout (floats)
    float* ws    = (float*)d_ws;
    float* bufA  = ws;                             // 64,000,000 f
    float* bufB  = bufA + 64000000;                // 64,000,000 f
    float* dinv  = bufB + 64000000;                // 524,288 f
    float* zpad  = dinv + 524288;                  // 1,310,720 f
    float* w1pad = zpad + (size_t)N_GRAPHS * 80;   // 163,840 f
    float* whcat = w1pad + 80 * 2048;              // 32,768 f
    float* bh1p  = whcat + 128 * 256;              // 256 f
    int* counts  = (int*)(bh1p + 256);             // 500,000
    int* row_ptr = counts + N_NODES;               // 500,224
    int* cursor  = row_ptr + 500224;               // 500,000
    int* srcs    = cursor + N_NODES;               // 2,000,000
    int* bsum    = srcs + N_EDGES;                 // 256
    int* boff    = bsum + 256;                     // 256
    int* gstart  = boff + 256;                     // 16,640
    int* gcnt    = gstart + 16640;                 // 16,384
    float* P     = bufB + 61902848;                // 2,097,152 f (inside dead agg1 tail)

    // hi/lo activations & weights (carved from bufA/bufB, timeline-disjoint)
    unsigned short* z1h = (unsigned short*)bufB;                // 33.55M u16
    unsigned short* z1l = (unsigned short*)(bufB + 16800000);   // 33.55M u16
    unsigned short* z2h = (unsigned short*)bufA;                // 16.78M u16
    unsigned short* z2l = (unsigned short*)(bufA + 8400000);    // 16.78M u16
    float* z3 = bufB + 34000000;                                // 2.10M f
    unsigned short* w2th = (unsigned short*)(bufA + 17000000);  // 2.10M u16
    unsigned short* w2tl = (unsigned short*)(bufA + 18100000);  // 2.10M u16
    unsigned short* w3th = (unsigned short*)(bufA + 19200000);  // 131K u16
    unsigned short* w3tl = (unsigned short*)(bufA + 19300000);  // 131K u16
    float* ab = bufA + 20000000;                                // 4.19M f

    // 1) CSR build + dinv + graph segments
    k_zero_counts<<<(N_NODES + 255) / 256, 256, 0, stream>>>(counts);
    k_hist<<<(N_EDGES + 255) / 256, 256, 0, stream>>>(edst, counts);
    k_scan_reduce<<<SCAN_NBLK, 256, 0, stream>>>(counts, bsum);
    k_scan_bsum<<<1, 256, 0, stream>>>(bsum, boff, row_ptr);
    k_scan_final<<<SCAN_NBLK, 256, 0, stream>>>(counts, boff, row_ptr, cursor, dinv);
    k_fill<<<(N_EDGES + 255) / 256, 256, 0, stream>>>(esrc, edst, cursor, srcs);
    k_gstart<<<(N_GRAPHS + 256) / 256, 256, 0, stream>>>(batch, gstart);

    // 2) conv1: hpre = x @ Wc1 -> bufA ; gather -> agg1 (bufB)
    k_gemm_conv1<131><<<(N_NODES + 127) / 128, 256, 0, stream>>>(x, Wc1, bufA, N_NODES);
    k_gather1<<<(N_NODES * 64) / 256, 256, 0, stream>>>(bufA, dinv, bc1, row_ptr, srcs, bufB);

    // 3) conv2 reassociated: ah -> bufA ; pool -> P ; zpad
    k_gather2<<<(N_NODES * 64) / 256, 256, 0, stream>>>(bufB, dinv, row_ptr, srcs, bufA);
    k_pool_seg<<<N_GRAPHS, 256, 0, stream>>>(bufA, gstart, P, gcnt);

    // weight transposes+splits (bufA free after pool)
    k_tsplit<<<dim3(1024 / 64, 2048 / 64), 256, 0, stream>>>(W2, 2048, 1024, w2th, w2tl);
    k_tsplit<<<dim3(128 / 64, 1024 / 64), 256, 0, stream>>>(W3, 1024, 128, w3th, w3tl);

    k_zg<<<N_GRAPHS, 128, 0, stream>>>(P, gcnt, Wc2, bc2, solv, zpad);

    // 4) MLP
    k_w1pad<<<(80 * 2048) / 256, 256, 0, stream>>>(W1, w1pad);
    k_whcat<<<(128 * 256) / 256, 256, 0, stream>>>(Wh1, whcat);
    k_bh1pad<<<1, 256, 0, stream>>>(bh1, bh1p);

    // W1 (fp32, K=80) -> z1 hi/lo
    k_gemm<true, 1><<<dim3(2048 / 128, N_GRAPHS / 128), 256, 0, stream>>>(
        zpad, w1pad, b1, nullptr, z1h, z1l, N_GRAPHS, 2048, 80);
    // W2 (split-bf16 MFMA, K=2048) -> z2 hi/lo
    k_mfma_split<1><<<(1024 / 128) * (N_GRAPHS / 128), 256, 0, stream>>>(
        z1h, z1l, w2th, w2tl, b2, nullptr, z2h, z2l, 1024, 2048);
    // W3 (split-bf16 MFMA, K=1024) -> z3 fp32
    k_mfma_split<0><<<(128 / 128) * (N_GRAPHS / 128), 256, 0, stream>>>(
        z2h, z2l, w3th, w3tl, b3, z3, nullptr, nullptr, 128, 1024);

    // 5) heads (fp32, K=128)
    k_gemm<true, 0><<<dim3(256 / 128, N_GRAPHS / 128), 256, 0, stream>>>(
        z3, whcat, bh1p, ab, nullptr, nullptr, N_GRAPHS, 256, 128);
    k_heads_out<<<(N_GRAPHS * 6 + 255) / 256, 256, 0, stream>>>(ab, Wh2, bh2, out);
}